// Round 1
// baseline (5356.319 us; speedup 1.0000x reference)
//
#include <hip/hip_runtime.h>
#include <hip/hip_bf16.h>

#define N_ROI 512
#define M_REF 4096
#define FEAT 1024
#define GROUP 16
#define DG 64
#define EMB 64

// ---------------------------------------------------------------------------
// GEMM: C[i,j] = sum_k A[i,k] * W[j,k] + b[j]   (A [M x K] rowmajor, W [N x K] rowmajor)
// BM=BN=64, BK=16, 256 threads, 4x4 per thread.
// ---------------------------------------------------------------------------
__global__ __launch_bounds__(256) void gemm_nt_bias(
    const float* __restrict__ A, const float* __restrict__ W,
    const float* __restrict__ b, float* __restrict__ C,
    int M, int N, int K) {
  __shared__ float As[64][17];
  __shared__ float Ws[64][17];
  const int tid = threadIdx.x;
  const int bm = blockIdx.y * 64, bn = blockIdx.x * 64;
  const int tr = (tid / 16) * 4, tc = (tid % 16) * 4;
  float acc[4][4] = {};
  for (int k0 = 0; k0 < K; k0 += 16) {
    for (int i = tid; i < 64 * 16; i += 256) {
      int r = i >> 4, c = i & 15;
      As[r][c] = A[(size_t)(bm + r) * K + k0 + c];
      Ws[r][c] = W[(size_t)(bn + r) * K + k0 + c];
    }
    __syncthreads();
#pragma unroll
    for (int kk = 0; kk < 16; ++kk) {
      float a[4], w[4];
#pragma unroll
      for (int i = 0; i < 4; ++i) a[i] = As[tr + i][kk];
#pragma unroll
      for (int j = 0; j < 4; ++j) w[j] = Ws[tc + j][kk];
#pragma unroll
      for (int i = 0; i < 4; ++i)
#pragma unroll
        for (int j = 0; j < 4; ++j) acc[i][j] += a[i] * w[j];
    }
    __syncthreads();
  }
#pragma unroll
  for (int i = 0; i < 4; ++i)
#pragma unroll
    for (int j = 0; j < 4; ++j)
      C[(size_t)(bm + tr + i) * N + bn + tc + j] = acc[i][j] + b[bn + tc + j];
}

// ---------------------------------------------------------------------------
// aff[n,g,m] = log(relu(emb(n,m)·Wg_w[g] + Wg_b[g]) + 1e-6)
// one thread per (n,m); Wg staged in LDS.
// ---------------------------------------------------------------------------
__global__ __launch_bounds__(256) void aff_weight_kernel(
    const float* __restrict__ rois_cur, const float* __restrict__ rois_ref,
    const float* __restrict__ Wg_w, const float* __restrict__ Wg_b,
    float* __restrict__ aff) {
  __shared__ float wg[GROUP][EMB];
  __shared__ float wgb[GROUP];
  const int n = blockIdx.y;
  const int m = blockIdx.x * 256 + threadIdx.x;
  for (int i = threadIdx.x; i < GROUP * EMB; i += 256) wg[i >> 6][i & 63] = Wg_w[i];
  if (threadIdx.x < GROUP) wgb[threadIdx.x] = Wg_b[threadIdx.x];
  __syncthreads();

  const float x0 = rois_cur[n * 4 + 0], y0 = rois_cur[n * 4 + 1];
  const float x1 = rois_cur[n * 4 + 2], y1 = rois_cur[n * 4 + 3];
  const float w = x1 - x0 + 1.0f, h = y1 - y0 + 1.0f;
  const float cx = 0.5f * (x0 + x1), cy = 0.5f * (y0 + y1);

  const float4 rb = reinterpret_cast<const float4*>(rois_ref)[m];
  const float wr = rb.z - rb.x + 1.0f, hr = rb.w - rb.y + 1.0f;
  const float cxr = 0.5f * (rb.x + rb.z), cyr = 0.5f * (rb.y + rb.w);

  float pos[4];
  pos[0] = logf(fabsf((cx - cxr) / w) + 0.001f);
  pos[1] = logf(fabsf((cy - cyr) / h) + 0.001f);
  pos[2] = logf(w / wr);
  pos[3] = logf(h / hr);

  // dim_mat[f] = 1000^(f/8)
  const float dim_mat[8] = {1.0f, 2.3713737f, 5.6234131f, 13.335214f,
                            31.622776f, 74.989418f, 177.82794f, 421.69650f};

  float acc[GROUP] = {};
#pragma unroll
  for (int d = 0; d < 4; ++d) {
    const float p100 = pos[d] * 100.0f;
#pragma unroll
    for (int f = 0; f < 8; ++f) {
      float s, c;
      sincosf(p100 / dim_mat[f], &s, &c);
#pragma unroll
      for (int g = 0; g < GROUP; ++g)
        acc[g] += s * wg[g][d * 16 + f] + c * wg[g][d * 16 + 8 + f];
    }
  }
#pragma unroll
  for (int g = 0; g < GROUP; ++g) {
    float v = fmaxf(acc[g] + wgb[g], 0.0f);
    aff[((size_t)n * GROUP + g) * M_REF + m] = logf(v + 1e-6f);
  }
}

// ---------------------------------------------------------------------------
// aff[n,g,m] += dot(q[n,g,:], k[m,g,:]) / 8     (batched over g; K=64)
// grid (M/64, N/64, GROUP)
// ---------------------------------------------------------------------------
__global__ __launch_bounds__(256) void aff_scale_kernel(
    const float* __restrict__ q, const float* __restrict__ k,
    float* __restrict__ aff) {
  __shared__ float Qs[64][17];
  __shared__ float Ks[64][17];
  const int g = blockIdx.z;
  const int bn = blockIdx.y * 64, bm = blockIdx.x * 64;
  const int tid = threadIdx.x;
  const int tr = (tid / 16) * 4, tc = (tid % 16) * 4;
  float acc[4][4] = {};
  for (int k0 = 0; k0 < DG; k0 += 16) {
    for (int i = tid; i < 64 * 16; i += 256) {
      int r = i >> 4, c = i & 15;
      Qs[r][c] = q[(size_t)(bn + r) * FEAT + g * DG + k0 + c];
      Ks[r][c] = k[(size_t)(bm + r) * FEAT + g * DG + k0 + c];
    }
    __syncthreads();
#pragma unroll
    for (int kk = 0; kk < 16; ++kk) {
      float a[4], w[4];
#pragma unroll
      for (int i = 0; i < 4; ++i) a[i] = Qs[tr + i][kk];
#pragma unroll
      for (int j = 0; j < 4; ++j) w[j] = Ks[tc + j][kk];
#pragma unroll
      for (int i = 0; i < 4; ++i)
#pragma unroll
        for (int j = 0; j < 4; ++j) acc[i][j] += a[i] * w[j];
    }
    __syncthreads();
  }
#pragma unroll
  for (int i = 0; i < 4; ++i)
#pragma unroll
    for (int j = 0; j < 4; ++j) {
      size_t idx = ((size_t)(bn + tr + i) * GROUP + g) * M_REF + bm + tc + j;
      aff[idx] += acc[i][j] * 0.125f;
    }
}

// ---------------------------------------------------------------------------
// row softmax over M=4096; one block (256 threads) per (n,g) row.
// ---------------------------------------------------------------------------
__device__ __forceinline__ float waveMax(float v) {
#pragma unroll
  for (int o = 32; o > 0; o >>= 1) v = fmaxf(v, __shfl_xor(v, o));
  return v;
}
__device__ __forceinline__ float waveSum(float v) {
#pragma unroll
  for (int o = 32; o > 0; o >>= 1) v += __shfl_xor(v, o);
  return v;
}

__global__ __launch_bounds__(256) void softmax_kernel(float* __restrict__ aff) {
  __shared__ float red[4];
  float* p = aff + (size_t)blockIdx.x * M_REF;
  const int t = threadIdx.x;
  const int wave = t >> 6;
  float v[16];
  float lmax = -1e30f;
#pragma unroll
  for (int i = 0; i < 16; ++i) {
    v[i] = p[t + i * 256];
    lmax = fmaxf(lmax, v[i]);
  }
  lmax = waveMax(lmax);
  if ((t & 63) == 0) red[wave] = lmax;
  __syncthreads();
  float gmax = fmaxf(fmaxf(red[0], red[1]), fmaxf(red[2], red[3]));
  float lsum = 0.0f;
#pragma unroll
  for (int i = 0; i < 16; ++i) {
    v[i] = __expf(v[i] - gmax);
    lsum += v[i];
  }
  lsum = waveSum(lsum);
  __syncthreads();
  if ((t & 63) == 0) red[wave] = lsum;
  __syncthreads();
  float inv = 1.0f / (red[0] + red[1] + red[2] + red[3]);
#pragma unroll
  for (int i = 0; i < 16; ++i) p[t + i * 256] = v[i] * inv;
}

// ---------------------------------------------------------------------------
// out init with bias
// ---------------------------------------------------------------------------
__global__ __launch_bounds__(256) void init_out_kernel(
    const float* __restrict__ b, float* __restrict__ out) {
  int i = blockIdx.x * 256 + threadIdx.x;
  if (i < N_ROI * FEAT) out[i] = b[i & (FEAT - 1)];
}

// ---------------------------------------------------------------------------
// out[n, g*64+o] += sum_m soft[n,g,m] * V[m, g*64+o]
// grid (GROUP, N/64, 4 k-chunks); split-K with fp32 atomics.
// ---------------------------------------------------------------------------
__global__ __launch_bounds__(256) void pv_kernel(
    const float* __restrict__ aff, const float* __restrict__ V,
    float* __restrict__ out) {
  __shared__ float As[64][17];
  __shared__ float Bs[16][65];
  const int g = blockIdx.x;
  const int bn = blockIdx.y * 64;
  const int kchunk = blockIdx.z;
  const int tid = threadIdx.x;
  const int tr = (tid / 16) * 4, tc = (tid % 16) * 4;
  float acc[4][4] = {};
  const int m0 = kchunk * (M_REF / 4), m1 = m0 + (M_REF / 4);
  for (int mb = m0; mb < m1; mb += 16) {
    for (int i = tid; i < 64 * 16; i += 256) {
      int r = i >> 4, c = i & 15;
      As[r][c] = aff[((size_t)(bn + r) * GROUP + g) * M_REF + mb + c];
    }
    for (int i = tid; i < 16 * 64; i += 256) {
      int r = i >> 6, c = i & 63;
      Bs[r][c] = V[(size_t)(mb + r) * FEAT + g * DG + c];
    }
    __syncthreads();
#pragma unroll
    for (int kk = 0; kk < 16; ++kk) {
      float a[4], w[4];
#pragma unroll
      for (int i = 0; i < 4; ++i) a[i] = As[tr + i][kk];
#pragma unroll
      for (int j = 0; j < 4; ++j) w[j] = Bs[kk][tc + j];
#pragma unroll
      for (int i = 0; i < 4; ++i)
#pragma unroll
        for (int j = 0; j < 4; ++j) acc[i][j] += a[i] * w[j];
    }
    __syncthreads();
  }
#pragma unroll
  for (int i = 0; i < 4; ++i)
#pragma unroll
    for (int j = 0; j < 4; ++j)
      atomicAdd(&out[(size_t)(bn + tr + i) * FEAT + g * DG + tc + j],
                acc[i][j]);
}

// ---------------------------------------------------------------------------
extern "C" void kernel_launch(void* const* d_in, const int* in_sizes, int n_in,
                              void* d_out, int out_size, void* d_ws,
                              size_t ws_size, hipStream_t stream) {
  const float* roi_feat = (const float*)d_in[0];   // [512,1024]
  const float* ref_feat = (const float*)d_in[1];   // [4096,1024]
  const float* rois_cur = (const float*)d_in[2];   // [512,4]
  const float* rois_ref = (const float*)d_in[3];   // [4096,4]
  const float* Wg_w = (const float*)d_in[4];       // [16,64]
  const float* Wg_b = (const float*)d_in[5];       // [16]
  const float* Wq_w = (const float*)d_in[6];       // [1024,1024]
  const float* Wq_b = (const float*)d_in[7];       // [1024]
  const float* Wk_w = (const float*)d_in[8];       // [1024,1024]
  const float* Wk_b = (const float*)d_in[9];       // [1024]
  const float* Wv_w = (const float*)d_in[10];      // [1024,1024]
  const float* Wv_b = (const float*)d_in[11];      // [1024]
  float* out = (float*)d_out;                      // [512,1024]

  float* ws = (float*)d_ws;
  float* q = ws;                                   // 512*1024
  float* k = q + (size_t)N_ROI * FEAT;             // 4096*1024
  float* V = k + (size_t)M_REF * FEAT;             // 4096*1024
  float* aff = V + (size_t)M_REF * FEAT;           // 512*16*4096

  // 1. Q / K / V projections
  gemm_nt_bias<<<dim3(FEAT / 64, N_ROI / 64), 256, 0, stream>>>(
      roi_feat, Wq_w, Wq_b, q, N_ROI, FEAT, FEAT);
  gemm_nt_bias<<<dim3(FEAT / 64, M_REF / 64), 256, 0, stream>>>(
      ref_feat, Wk_w, Wk_b, k, M_REF, FEAT, FEAT);
  gemm_nt_bias<<<dim3(FEAT / 64, M_REF / 64), 256, 0, stream>>>(
      ref_feat, Wv_w, Wv_b, V, M_REF, FEAT, FEAT);

  // 2. positional log-weight
  aff_weight_kernel<<<dim3(M_REF / 256, N_ROI), 256, 0, stream>>>(
      rois_cur, rois_ref, Wg_w, Wg_b, aff);

  // 3. + scaled q·k
  aff_scale_kernel<<<dim3(M_REF / 64, N_ROI / 64, GROUP), 256, 0, stream>>>(
      q, k, aff);

  // 4. softmax over m
  softmax_kernel<<<dim3(N_ROI * GROUP), 256, 0, stream>>>(aff);

  // 5. out = softmax @ V + Wv_b   (note: V already holds ref_feat@Wv^T; bias
  //    added via init since softmax rows sum to 1 -> bias passes through; we
  //    add the true bias here and atomically accumulate the PV product)
  init_out_kernel<<<dim3((N_ROI * FEAT + 255) / 256), 256, 0, stream>>>(Wv_b,
                                                                        out);
  pv_kernel<<<dim3(GROUP, N_ROI / 64, 4), 256, 0, stream>>>(aff, V, out);
}

// Round 2
// 1076.239 us; speedup vs baseline: 4.9769x; 4.9769x over previous
//
#include <hip/hip_runtime.h>
#include <hip/hip_bf16.h>

#define N_ROI 512
#define M_REF 4096
#define FEAT 1024
#define GROUP 16
#define DG 64
#define EMB 64

// ---------------------------------------------------------------------------
// GEMM: C[i,j] = sum_k A[i,k] * W[j,k] + b[j]   (A [M x K] rowmajor, W [N x K] rowmajor)
// BM=BN=64, BK=16, 256 threads, 4x4 per thread.
// ---------------------------------------------------------------------------
__global__ __launch_bounds__(256) void gemm_nt_bias(
    const float* __restrict__ A, const float* __restrict__ W,
    const float* __restrict__ b, float* __restrict__ C,
    int M, int N, int K) {
  __shared__ float As[64][17];
  __shared__ float Ws[64][17];
  const int tid = threadIdx.x;
  const int bm = blockIdx.y * 64, bn = blockIdx.x * 64;
  const int tr = (tid / 16) * 4, tc = (tid % 16) * 4;
  float acc[4][4] = {};
  for (int k0 = 0; k0 < K; k0 += 16) {
    for (int i = tid; i < 64 * 16; i += 256) {
      int r = i >> 4, c = i & 15;
      As[r][c] = A[(size_t)(bm + r) * K + k0 + c];
      Ws[r][c] = W[(size_t)(bn + r) * K + k0 + c];
    }
    __syncthreads();
#pragma unroll
    for (int kk = 0; kk < 16; ++kk) {
      float a[4], w[4];
#pragma unroll
      for (int i = 0; i < 4; ++i) a[i] = As[tr + i][kk];
#pragma unroll
      for (int j = 0; j < 4; ++j) w[j] = Ws[tc + j][kk];
#pragma unroll
      for (int i = 0; i < 4; ++i)
#pragma unroll
        for (int j = 0; j < 4; ++j) acc[i][j] += a[i] * w[j];
    }
    __syncthreads();
  }
#pragma unroll
  for (int i = 0; i < 4; ++i)
#pragma unroll
    for (int j = 0; j < 4; ++j)
      C[(size_t)(bm + tr + i) * N + bn + tc + j] = acc[i][j] + b[bn + tc + j];
}

// ---------------------------------------------------------------------------
// aff[n,g,m] = log(relu(emb(n,m)·Wg_w[g] + Wg_b[g]) + 1e-6)
// one thread per (n,m); Wg staged in LDS.
// Hardware transcendentals (__sinf/__cosf/__logf): no libcall, no scratch.
// ---------------------------------------------------------------------------
__global__ __launch_bounds__(256) void aff_weight_kernel(
    const float* __restrict__ rois_cur, const float* __restrict__ rois_ref,
    const float* __restrict__ Wg_w, const float* __restrict__ Wg_b,
    float* __restrict__ aff) {
  __shared__ float wg[GROUP][EMB];
  __shared__ float wgb[GROUP];
  const int n = blockIdx.y;
  const int m = blockIdx.x * 256 + threadIdx.x;
  for (int i = threadIdx.x; i < GROUP * EMB; i += 256) wg[i >> 6][i & 63] = Wg_w[i];
  if (threadIdx.x < GROUP) wgb[threadIdx.x] = Wg_b[threadIdx.x];
  __syncthreads();

  const float x0 = rois_cur[n * 4 + 0], y0 = rois_cur[n * 4 + 1];
  const float x1 = rois_cur[n * 4 + 2], y1 = rois_cur[n * 4 + 3];
  const float w = x1 - x0 + 1.0f, h = y1 - y0 + 1.0f;
  const float cx = 0.5f * (x0 + x1), cy = 0.5f * (y0 + y1);

  const float4 rb = reinterpret_cast<const float4*>(rois_ref)[m];
  const float wr = rb.z - rb.x + 1.0f, hr = rb.w - rb.y + 1.0f;
  const float cxr = 0.5f * (rb.x + rb.z), cyr = 0.5f * (rb.y + rb.w);

  float pos[4];
  pos[0] = __logf(fabsf((cx - cxr) / w) + 0.001f);
  pos[1] = __logf(fabsf((cy - cyr) / h) + 0.001f);
  pos[2] = __logf(w / wr);
  pos[3] = __logf(h / hr);

  // inv_dim[f] = 1000^(-f/8)
  const float inv_dim[8] = {1.0f,          0.42169651f,  0.17782794f,
                            0.074989417f,  0.031622776f, 0.013335214f,
                            0.0056234133f, 0.0023713737f};

  float acc[GROUP] = {};
#pragma unroll
  for (int d = 0; d < 4; ++d) {
    const float p100 = pos[d] * 100.0f;
#pragma unroll
    for (int f = 0; f < 8; ++f) {
      const float x = p100 * inv_dim[f];
      const float s = __sinf(x);
      const float c = __cosf(x);
#pragma unroll
      for (int g = 0; g < GROUP; ++g)
        acc[g] += s * wg[g][d * 16 + f] + c * wg[g][d * 16 + 8 + f];
    }
  }
#pragma unroll
  for (int g = 0; g < GROUP; ++g) {
    float v = fmaxf(acc[g] + wgb[g], 0.0f);
    aff[((size_t)n * GROUP + g) * M_REF + m] = __logf(v + 1e-6f);
  }
}

// ---------------------------------------------------------------------------
// aff[n,g,m] += dot(q[n,g,:], k[m,g,:]) / 8     (batched over g; K=64)
// grid (M/64, N/64, GROUP)
// ---------------------------------------------------------------------------
__global__ __launch_bounds__(256) void aff_scale_kernel(
    const float* __restrict__ q, const float* __restrict__ k,
    float* __restrict__ aff) {
  __shared__ float Qs[64][17];
  __shared__ float Ks[64][17];
  const int g = blockIdx.z;
  const int bn = blockIdx.y * 64, bm = blockIdx.x * 64;
  const int tid = threadIdx.x;
  const int tr = (tid / 16) * 4, tc = (tid % 16) * 4;
  float acc[4][4] = {};
  for (int k0 = 0; k0 < DG; k0 += 16) {
    for (int i = tid; i < 64 * 16; i += 256) {
      int r = i >> 4, c = i & 15;
      Qs[r][c] = q[(size_t)(bn + r) * FEAT + g * DG + k0 + c];
      Ks[r][c] = k[(size_t)(bm + r) * FEAT + g * DG + k0 + c];
    }
    __syncthreads();
#pragma unroll
    for (int kk = 0; kk < 16; ++kk) {
      float a[4], w[4];
#pragma unroll
      for (int i = 0; i < 4; ++i) a[i] = Qs[tr + i][kk];
#pragma unroll
      for (int j = 0; j < 4; ++j) w[j] = Ks[tc + j][kk];
#pragma unroll
      for (int i = 0; i < 4; ++i)
#pragma unroll
        for (int j = 0; j < 4; ++j) acc[i][j] += a[i] * w[j];
    }
    __syncthreads();
  }
#pragma unroll
  for (int i = 0; i < 4; ++i)
#pragma unroll
    for (int j = 0; j < 4; ++j) {
      size_t idx = ((size_t)(bn + tr + i) * GROUP + g) * M_REF + bm + tc + j;
      aff[idx] += acc[i][j] * 0.125f;
    }
}

// ---------------------------------------------------------------------------
// row softmax over M=4096; one block (256 threads) per (n,g) row.
// ---------------------------------------------------------------------------
__device__ __forceinline__ float waveMax(float v) {
#pragma unroll
  for (int o = 32; o > 0; o >>= 1) v = fmaxf(v, __shfl_xor(v, o));
  return v;
}
__device__ __forceinline__ float waveSum(float v) {
#pragma unroll
  for (int o = 32; o > 0; o >>= 1) v += __shfl_xor(v, o);
  return v;
}

__global__ __launch_bounds__(256) void softmax_kernel(float* __restrict__ aff) {
  __shared__ float red[4];
  float* p = aff + (size_t)blockIdx.x * M_REF;
  const int t = threadIdx.x;
  const int wave = t >> 6;
  float v[16];
  float lmax = -1e30f;
#pragma unroll
  for (int i = 0; i < 16; ++i) {
    v[i] = p[t + i * 256];
    lmax = fmaxf(lmax, v[i]);
  }
  lmax = waveMax(lmax);
  if ((t & 63) == 0) red[wave] = lmax;
  __syncthreads();
  float gmax = fmaxf(fmaxf(red[0], red[1]), fmaxf(red[2], red[3]));
  float lsum = 0.0f;
#pragma unroll
  for (int i = 0; i < 16; ++i) {
    v[i] = __expf(v[i] - gmax);
    lsum += v[i];
  }
  lsum = waveSum(lsum);
  __syncthreads();
  if ((t & 63) == 0) red[wave] = lsum;
  __syncthreads();
  float inv = 1.0f / (red[0] + red[1] + red[2] + red[3]);
#pragma unroll
  for (int i = 0; i < 16; ++i) p[t + i * 256] = v[i] * inv;
}

// ---------------------------------------------------------------------------
// out init with bias
// ---------------------------------------------------------------------------
__global__ __launch_bounds__(256) void init_out_kernel(
    const float* __restrict__ b, float* __restrict__ out) {
  int i = blockIdx.x * 256 + threadIdx.x;
  if (i < N_ROI * FEAT) out[i] = b[i & (FEAT - 1)];
}

// ---------------------------------------------------------------------------
// out[n, g*64+o] += sum_m soft[n,g,m] * V[m, g*64+o]
// grid (GROUP, N/64, 4 k-chunks); split-K with fp32 atomics.
// ---------------------------------------------------------------------------
__global__ __launch_bounds__(256) void pv_kernel(
    const float* __restrict__ aff, const float* __restrict__ V,
    float* __restrict__ out) {
  __shared__ float As[64][17];
  __shared__ float Bs[16][65];
  const int g = blockIdx.x;
  const int bn = blockIdx.y * 64;
  const int kchunk = blockIdx.z;
  const int tid = threadIdx.x;
  const int tr = (tid / 16) * 4, tc = (tid % 16) * 4;
  float acc[4][4] = {};
  const int m0 = kchunk * (M_REF / 4), m1 = m0 + (M_REF / 4);
  for (int mb = m0; mb < m1; mb += 16) {
    for (int i = tid; i < 64 * 16; i += 256) {
      int r = i >> 4, c = i & 15;
      As[r][c] = aff[((size_t)(bn + r) * GROUP + g) * M_REF + mb + c];
    }
    for (int i = tid; i < 16 * 64; i += 256) {
      int r = i >> 6, c = i & 63;
      Bs[r][c] = V[(size_t)(mb + r) * FEAT + g * DG + c];
    }
    __syncthreads();
#pragma unroll
    for (int kk = 0; kk < 16; ++kk) {
      float a[4], w[4];
#pragma unroll
      for (int i = 0; i < 4; ++i) a[i] = As[tr + i][kk];
#pragma unroll
      for (int j = 0; j < 4; ++j) w[j] = Bs[kk][tc + j];
#pragma unroll
      for (int i = 0; i < 4; ++i)
#pragma unroll
        for (int j = 0; j < 4; ++j) acc[i][j] += a[i] * w[j];
    }
    __syncthreads();
  }
#pragma unroll
  for (int i = 0; i < 4; ++i)
#pragma unroll
    for (int j = 0; j < 4; ++j)
      atomicAdd(&out[(size_t)(bn + tr + i) * FEAT + g * DG + tc + j],
                acc[i][j]);
}

// ---------------------------------------------------------------------------
extern "C" void kernel_launch(void* const* d_in, const int* in_sizes, int n_in,
                              void* d_out, int out_size, void* d_ws,
                              size_t ws_size, hipStream_t stream) {
  const float* roi_feat = (const float*)d_in[0];   // [512,1024]
  const float* ref_feat = (const float*)d_in[1];   // [4096,1024]
  const float* rois_cur = (const float*)d_in[2];   // [512,4]
  const float* rois_ref = (const float*)d_in[3];   // [4096,4]
  const float* Wg_w = (const float*)d_in[4];       // [16,64]
  const float* Wg_b = (const float*)d_in[5];       // [16]
  const float* Wq_w = (const float*)d_in[6];       // [1024,1024]
  const float* Wq_b = (const float*)d_in[7];       // [1024]
  const float* Wk_w = (const float*)d_in[8];       // [1024,1024]
  const float* Wk_b = (const float*)d_in[9];       // [1024]
  const float* Wv_w = (const float*)d_in[10];      // [1024,1024]
  const float* Wv_b = (const float*)d_in[11];      // [1024]
  float* out = (float*)d_out;                      // [512,1024]

  float* ws = (float*)d_ws;
  float* q = ws;                                   // 512*1024
  float* k = q + (size_t)N_ROI * FEAT;             // 4096*1024
  float* V = k + (size_t)M_REF * FEAT;             // 4096*1024
  float* aff = V + (size_t)M_REF * FEAT;           // 512*16*4096

  // 1. Q / K / V projections
  gemm_nt_bias<<<dim3(FEAT / 64, N_ROI / 64), 256, 0, stream>>>(
      roi_feat, Wq_w, Wq_b, q, N_ROI, FEAT, FEAT);
  gemm_nt_bias<<<dim3(FEAT / 64, M_REF / 64), 256, 0, stream>>>(
      ref_feat, Wk_w, Wk_b, k, M_REF, FEAT, FEAT);
  gemm_nt_bias<<<dim3(FEAT / 64, M_REF / 64), 256, 0, stream>>>(
      ref_feat, Wv_w, Wv_b, V, M_REF, FEAT, FEAT);

  // 2. positional log-weight
  aff_weight_kernel<<<dim3(M_REF / 256, N_ROI), 256, 0, stream>>>(
      rois_cur, rois_ref, Wg_w, Wg_b, aff);

  // 3. + scaled q·k
  aff_scale_kernel<<<dim3(M_REF / 64, N_ROI / 64, GROUP), 256, 0, stream>>>(
      q, k, aff);

  // 4. softmax over m
  softmax_kernel<<<dim3(N_ROI * GROUP), 256, 0, stream>>>(aff);

  // 5. out = softmax @ V + Wv_b
  init_out_kernel<<<dim3((N_ROI * FEAT + 255) / 256), 256, 0, stream>>>(Wv_b,
                                                                        out);
  pv_kernel<<<dim3(GROUP, N_ROI / 64, 4), 256, 0, stream>>>(aff, V, out);
}

// Round 3
// 428.658 us; speedup vs baseline: 12.4956x; 2.5107x over previous
//
#include <hip/hip_runtime.h>
#include <hip/hip_bf16.h>

#define N_ROI 512
#define M_REF 4096
#define FEAT 1024
#define GROUP 16
#define DG 64
#define EMB 64
#define LDH 40  // fp16 LDS row stride: 32 + 8 pad -> period-8 bank pattern, b128-aligned

using f16x8 = __attribute__((ext_vector_type(8))) _Float16;
using f16x4 = __attribute__((ext_vector_type(4))) _Float16;
using f32x4 = __attribute__((ext_vector_type(4))) float;

// ---------------------------------------------------------------------------
// NT GEMM, fp32 in (cvt to f16 in staging), f16 out:
//   C[i,j] = (f16)( sum_k A[i,k]*W[j,k] + bias[j] )
// BM=BN=128, BK=32, 256 threads = 4 waves (2x2), each wave 64x64 (4x4 MFMA).
// ---------------------------------------------------------------------------
__global__ __launch_bounds__(256) void gemm_nt_f16(
    const float* __restrict__ A, const float* __restrict__ W,
    const float* __restrict__ bias, _Float16* __restrict__ C,
    int M, int N, int K) {
  __shared__ _Float16 As[128 * LDH];
  __shared__ _Float16 Bs[128 * LDH];
  const int tid = threadIdx.x;
  const int bm = blockIdx.y * 128, bn = blockIdx.x * 128;
  const int lane = tid & 63, wid = tid >> 6;
  const int wr = (wid >> 1) * 64, wc = (wid & 1) * 64;
  const int lrow = lane & 15, lk = (lane >> 4) * 8;
  f32x4 acc[4][4] = {};

  for (int k0 = 0; k0 < K; k0 += 32) {
#pragma unroll
    for (int i = 0; i < 4; ++i) {
      int idx = tid + i * 256;
      int r = idx >> 3, c4 = (idx & 7) * 4;
      float4 av = *(const float4*)&A[(size_t)(bm + r) * K + k0 + c4];
      float4 wv = *(const float4*)&W[(size_t)(bn + r) * K + k0 + c4];
      *(f16x4*)&As[r * LDH + c4] =
          f16x4{(_Float16)av.x, (_Float16)av.y, (_Float16)av.z, (_Float16)av.w};
      *(f16x4*)&Bs[r * LDH + c4] =
          f16x4{(_Float16)wv.x, (_Float16)wv.y, (_Float16)wv.z, (_Float16)wv.w};
    }
    __syncthreads();
    f16x8 a[4], b[4];
#pragma unroll
    for (int mi = 0; mi < 4; ++mi)
      a[mi] = *(const f16x8*)&As[(wr + mi * 16 + lrow) * LDH + lk];
#pragma unroll
    for (int ni = 0; ni < 4; ++ni)
      b[ni] = *(const f16x8*)&Bs[(wc + ni * 16 + lrow) * LDH + lk];
#pragma unroll
    for (int mi = 0; mi < 4; ++mi)
#pragma unroll
      for (int ni = 0; ni < 4; ++ni)
        acc[mi][ni] = __builtin_amdgcn_mfma_f32_16x16x32_f16(a[mi], b[ni],
                                                             acc[mi][ni], 0, 0, 0);
    __syncthreads();
  }
#pragma unroll
  for (int mi = 0; mi < 4; ++mi)
#pragma unroll
    for (int ni = 0; ni < 4; ++ni) {
      int col = bn + wc + ni * 16 + lrow;
      float bv = bias ? bias[col] : 0.0f;
#pragma unroll
      for (int i = 0; i < 4; ++i) {
        int row = bm + wr + mi * 16 + (lane >> 4) * 4 + i;
        C[(size_t)row * N + col] = (_Float16)(acc[mi][ni][i] + bv);
      }
    }
}

// ---------------------------------------------------------------------------
// aff[n,g,m] = log(relu(emb(n,m)·Wg_w[g] + Wg_b[g]) + 1e-6)
// ---------------------------------------------------------------------------
__global__ __launch_bounds__(256) void aff_weight_kernel(
    const float* __restrict__ rois_cur, const float* __restrict__ rois_ref,
    const float* __restrict__ Wg_w, const float* __restrict__ Wg_b,
    float* __restrict__ aff) {
  __shared__ float wg[GROUP][EMB];
  __shared__ float wgb[GROUP];
  const int n = blockIdx.y;
  const int m = blockIdx.x * 256 + threadIdx.x;
  for (int i = threadIdx.x; i < GROUP * EMB; i += 256) wg[i >> 6][i & 63] = Wg_w[i];
  if (threadIdx.x < GROUP) wgb[threadIdx.x] = Wg_b[threadIdx.x];
  __syncthreads();

  const float x0 = rois_cur[n * 4 + 0], y0 = rois_cur[n * 4 + 1];
  const float x1 = rois_cur[n * 4 + 2], y1 = rois_cur[n * 4 + 3];
  const float w = x1 - x0 + 1.0f, h = y1 - y0 + 1.0f;
  const float cx = 0.5f * (x0 + x1), cy = 0.5f * (y0 + y1);

  const float4 rb = reinterpret_cast<const float4*>(rois_ref)[m];
  const float wr = rb.z - rb.x + 1.0f, hr = rb.w - rb.y + 1.0f;
  const float cxr = 0.5f * (rb.x + rb.z), cyr = 0.5f * (rb.y + rb.w);

  float pos[4];
  pos[0] = __logf(fabsf((cx - cxr) / w) + 0.001f);
  pos[1] = __logf(fabsf((cy - cyr) / h) + 0.001f);
  pos[2] = __logf(w / wr);
  pos[3] = __logf(h / hr);

  const float inv_dim[8] = {1.0f,          0.42169651f,  0.17782794f,
                            0.074989417f,  0.031622776f, 0.013335214f,
                            0.0056234133f, 0.0023713737f};

  float acc[GROUP] = {};
#pragma unroll
  for (int d = 0; d < 4; ++d) {
    const float p100 = pos[d] * 100.0f;
#pragma unroll
    for (int f = 0; f < 8; ++f) {
      const float x = p100 * inv_dim[f];
      const float s = __sinf(x);
      const float c = __cosf(x);
#pragma unroll
      for (int g = 0; g < GROUP; ++g)
        acc[g] += s * wg[g][d * 16 + f] + c * wg[g][d * 16 + 8 + f];
    }
  }
#pragma unroll
  for (int g = 0; g < GROUP; ++g) {
    float v = fmaxf(acc[g] + wgb[g], 0.0f);
    aff[((size_t)n * GROUP + g) * M_REF + m] = __logf(v + 1e-6f);
  }
}

// ---------------------------------------------------------------------------
// aff[n,g,m] += dot(q16[n,g,:], k16[m,g,:]) * 0.125   via MFMA, K=64.
// grid (M/128, N/128, GROUP); BM=BN=128, BK=32.
// ---------------------------------------------------------------------------
__global__ __launch_bounds__(256) void aff_scale_mfma(
    const _Float16* __restrict__ q, const _Float16* __restrict__ k,
    float* __restrict__ aff) {
  __shared__ _Float16 Qs[128 * LDH];
  __shared__ _Float16 Ks[128 * LDH];
  const int tid = threadIdx.x;
  const int g = blockIdx.z;
  const int bn = blockIdx.y * 128, bm = blockIdx.x * 128;
  const int lane = tid & 63, wid = tid >> 6;
  const int wr = (wid >> 1) * 64, wc = (wid & 1) * 64;
  const int lrow = lane & 15, lk = (lane >> 4) * 8;
  f32x4 acc[4][4] = {};

  for (int k0 = 0; k0 < DG; k0 += 32) {
#pragma unroll
    for (int i = 0; i < 2; ++i) {
      int idx = tid + i * 256;
      int r = idx >> 2, c8 = (idx & 3) * 8;
      *(f16x8*)&Qs[r * LDH + c8] =
          *(const f16x8*)&q[(size_t)(bn + r) * FEAT + g * DG + k0 + c8];
      *(f16x8*)&Ks[r * LDH + c8] =
          *(const f16x8*)&k[(size_t)(bm + r) * FEAT + g * DG + k0 + c8];
    }
    __syncthreads();
    f16x8 a[4], b[4];
#pragma unroll
    for (int mi = 0; mi < 4; ++mi)
      a[mi] = *(const f16x8*)&Qs[(wr + mi * 16 + lrow) * LDH + lk];
#pragma unroll
    for (int ni = 0; ni < 4; ++ni)
      b[ni] = *(const f16x8*)&Ks[(wc + ni * 16 + lrow) * LDH + lk];
#pragma unroll
    for (int mi = 0; mi < 4; ++mi)
#pragma unroll
      for (int ni = 0; ni < 4; ++ni)
        acc[mi][ni] = __builtin_amdgcn_mfma_f32_16x16x32_f16(a[mi], b[ni],
                                                             acc[mi][ni], 0, 0, 0);
    __syncthreads();
  }
#pragma unroll
  for (int mi = 0; mi < 4; ++mi)
#pragma unroll
    for (int ni = 0; ni < 4; ++ni)
#pragma unroll
      for (int i = 0; i < 4; ++i) {
        int n = bn + wr + mi * 16 + (lane >> 4) * 4 + i;
        int m = bm + wc + ni * 16 + lrow;
        size_t idx = ((size_t)n * GROUP + g) * M_REF + m;
        aff[idx] += acc[mi][ni][i] * 0.125f;
      }
}

// ---------------------------------------------------------------------------
// row softmax over M=4096; one block per (n,g) row.
// ---------------------------------------------------------------------------
__device__ __forceinline__ float waveMax(float v) {
#pragma unroll
  for (int o = 32; o > 0; o >>= 1) v = fmaxf(v, __shfl_xor(v, o));
  return v;
}
__device__ __forceinline__ float waveSum(float v) {
#pragma unroll
  for (int o = 32; o > 0; o >>= 1) v += __shfl_xor(v, o);
  return v;
}

__global__ __launch_bounds__(256) void softmax_kernel(float* __restrict__ aff) {
  __shared__ float red[4];
  float* p = aff + (size_t)blockIdx.x * M_REF;
  const int t = threadIdx.x;
  const int wave = t >> 6;
  float v[16];
  float lmax = -1e30f;
#pragma unroll
  for (int i = 0; i < 16; ++i) {
    v[i] = p[t + i * 256];
    lmax = fmaxf(lmax, v[i]);
  }
  lmax = waveMax(lmax);
  if ((t & 63) == 0) red[wave] = lmax;
  __syncthreads();
  float gmax = fmaxf(fmaxf(red[0], red[1]), fmaxf(red[2], red[3]));
  float lsum = 0.0f;
#pragma unroll
  for (int i = 0; i < 16; ++i) {
    v[i] = __expf(v[i] - gmax);
    lsum += v[i];
  }
  lsum = waveSum(lsum);
  __syncthreads();
  if ((t & 63) == 0) red[wave] = lsum;
  __syncthreads();
  float inv = 1.0f / (red[0] + red[1] + red[2] + red[3]);
#pragma unroll
  for (int i = 0; i < 16; ++i) p[t + i * 256] = v[i] * inv;
}

// ---------------------------------------------------------------------------
__global__ __launch_bounds__(256) void init_out_kernel(
    const float* __restrict__ b, float* __restrict__ out) {
  int i = blockIdx.x * 256 + threadIdx.x;
  if (i < N_ROI * FEAT) out[i] = b[i & (FEAT - 1)];
}

// ---------------------------------------------------------------------------
// out[n, g*64+o] += sum_m P[n,g,m] * Vt[g*64+o, m]     (P cvt f16 in staging)
// grid (GROUP, N/128, 4 split-k); BM=128, BN=64, BK=32; waves 2x2, tile 64x32.
// ---------------------------------------------------------------------------
__global__ __launch_bounds__(256) void pv_mfma(
    const float* __restrict__ aff, const _Float16* __restrict__ vt,
    float* __restrict__ out) {
  __shared__ _Float16 As[128 * LDH];
  __shared__ _Float16 Bs[64 * LDH];
  const int tid = threadIdx.x;
  const int g = blockIdx.x;
  const int bn = blockIdx.y * 128;
  const int m0 = blockIdx.z * (M_REF / 4);
  const int lane = tid & 63, wid = tid >> 6;
  const int wr = (wid >> 1) * 64, wc = (wid & 1) * 32;
  const int lrow = lane & 15, lk = (lane >> 4) * 8;
  f32x4 acc[4][2] = {};

  for (int ks = 0; ks < M_REF / 4; ks += 32) {
#pragma unroll
    for (int i = 0; i < 4; ++i) {
      int idx = tid + i * 256;
      int r = idx >> 3, c4 = (idx & 7) * 4;
      float4 av = *(const float4*)
          &aff[((size_t)(bn + r) * GROUP + g) * M_REF + m0 + ks + c4];
      *(f16x4*)&As[r * LDH + c4] =
          f16x4{(_Float16)av.x, (_Float16)av.y, (_Float16)av.z, (_Float16)av.w};
    }
    {
      int r = tid >> 2, c8 = (tid & 3) * 8;
      *(f16x8*)&Bs[r * LDH + c8] =
          *(const f16x8*)&vt[(size_t)(g * DG + r) * M_REF + m0 + ks + c8];
    }
    __syncthreads();
    f16x8 a[4], b[2];
#pragma unroll
    for (int mi = 0; mi < 4; ++mi)
      a[mi] = *(const f16x8*)&As[(wr + mi * 16 + lrow) * LDH + lk];
#pragma unroll
    for (int ni = 0; ni < 2; ++ni)
      b[ni] = *(const f16x8*)&Bs[(wc + ni * 16 + lrow) * LDH + lk];
#pragma unroll
    for (int mi = 0; mi < 4; ++mi)
#pragma unroll
      for (int ni = 0; ni < 2; ++ni)
        acc[mi][ni] = __builtin_amdgcn_mfma_f32_16x16x32_f16(a[mi], b[ni],
                                                             acc[mi][ni], 0, 0, 0);
    __syncthreads();
  }
#pragma unroll
  for (int mi = 0; mi < 4; ++mi)
#pragma unroll
    for (int ni = 0; ni < 2; ++ni)
#pragma unroll
      for (int i = 0; i < 4; ++i) {
        int row = bn + wr + mi * 16 + (lane >> 4) * 4 + i;
        int col = g * DG + wc + ni * 16 + lrow;
        atomicAdd(&out[(size_t)row * FEAT + col], acc[mi][ni][i]);
      }
}

// ---------------------------------------------------------------------------
extern "C" void kernel_launch(void* const* d_in, const int* in_sizes, int n_in,
                              void* d_out, int out_size, void* d_ws,
                              size_t ws_size, hipStream_t stream) {
  const float* roi_feat = (const float*)d_in[0];   // [512,1024]
  const float* ref_feat = (const float*)d_in[1];   // [4096,1024]
  const float* rois_cur = (const float*)d_in[2];   // [512,4]
  const float* rois_ref = (const float*)d_in[3];   // [4096,4]
  const float* Wg_w = (const float*)d_in[4];       // [16,64]
  const float* Wg_b = (const float*)d_in[5];       // [16]
  const float* Wq_w = (const float*)d_in[6];       // [1024,1024]
  const float* Wq_b = (const float*)d_in[7];       // [1024]
  const float* Wk_w = (const float*)d_in[8];       // [1024,1024]
  const float* Wk_b = (const float*)d_in[9];       // [1024]
  const float* Wv_w = (const float*)d_in[10];      // [1024,1024]
  const float* Wv_b = (const float*)d_in[11];      // [1024]
  float* out = (float*)d_out;                      // [512,1024]

  _Float16* q16 = (_Float16*)d_ws;                     // 512*1024
  _Float16* k16 = q16 + (size_t)N_ROI * FEAT;          // 4096*1024
  _Float16* vt16 = k16 + (size_t)M_REF * FEAT;         // 1024*4096 (transposed V)
  float* aff = (float*)(vt16 + (size_t)FEAT * M_REF);  // 512*16*4096

  // 1. projections (f16 MFMA).  Vt computed directly transposed:
  //    vt[o,m] = sum_k Wv[o,k] * ref_feat[m,k]   (no bias; added in init_out)
  gemm_nt_f16<<<dim3(FEAT / 128, N_ROI / 128), 256, 0, stream>>>(
      roi_feat, Wq_w, Wq_b, q16, N_ROI, FEAT, FEAT);
  gemm_nt_f16<<<dim3(FEAT / 128, M_REF / 128), 256, 0, stream>>>(
      ref_feat, Wk_w, Wk_b, k16, M_REF, FEAT, FEAT);
  gemm_nt_f16<<<dim3(M_REF / 128, FEAT / 128), 256, 0, stream>>>(
      Wv_w, ref_feat, nullptr, vt16, FEAT, M_REF, FEAT);

  // 2. positional log-weight
  aff_weight_kernel<<<dim3(M_REF / 256, N_ROI), 256, 0, stream>>>(
      rois_cur, rois_ref, Wg_w, Wg_b, aff);

  // 3. + scaled q·k (MFMA)
  aff_scale_mfma<<<dim3(M_REF / 128, N_ROI / 128, GROUP), 256, 0, stream>>>(
      q16, k16, aff);

  // 4. softmax over m
  softmax_kernel<<<dim3(N_ROI * GROUP), 256, 0, stream>>>(aff);

  // 5. out = P @ Vt^T + Wv_b
  init_out_kernel<<<dim3((N_ROI * FEAT + 255) / 256), 256, 0, stream>>>(Wv_b,
                                                                        out);
  pv_mfma<<<dim3(GROUP, N_ROI / 128, 4), 256, 0, stream>>>(aff, vt16, out);
}

// Round 4
// 373.206 us; speedup vs baseline: 14.3522x; 1.1486x over previous
//
#include <hip/hip_runtime.h>
#include <hip/hip_bf16.h>

#define N_ROI 512
#define M_REF 4096
#define FEAT 1024
#define GROUP 16
#define DG 64
#define EMB 64
#define LDH 40  // fp16 LDS row stride for gemm staging
#define BP 68   // Bias LDS col pad (halfs)

using f16x8 = __attribute__((ext_vector_type(8))) _Float16;
using f16x4 = __attribute__((ext_vector_type(4))) _Float16;
using f32x4 = __attribute__((ext_vector_type(4))) float;

// ---------------------------------------------------------------------------
// NT GEMM, fp32 in (cvt to f16 in staging), f16 out (unchanged from R3).
// ---------------------------------------------------------------------------
__global__ __launch_bounds__(256) void gemm_nt_f16(
    const float* __restrict__ A, const float* __restrict__ W,
    const float* __restrict__ bias, _Float16* __restrict__ C,
    int M, int N, int K) {
  __shared__ _Float16 As[128 * LDH];
  __shared__ _Float16 Bs[128 * LDH];
  const int tid = threadIdx.x;
  const int bm = blockIdx.y * 128, bn = blockIdx.x * 128;
  const int lane = tid & 63, wid = tid >> 6;
  const int wr = (wid >> 1) * 64, wc = (wid & 1) * 64;
  const int lrow = lane & 15, lk = (lane >> 4) * 8;
  f32x4 acc[4][4] = {};

  for (int k0 = 0; k0 < K; k0 += 32) {
#pragma unroll
    for (int i = 0; i < 4; ++i) {
      int idx = tid + i * 256;
      int r = idx >> 3, c4 = (idx & 7) * 4;
      float4 av = *(const float4*)&A[(size_t)(bm + r) * K + k0 + c4];
      float4 wv = *(const float4*)&W[(size_t)(bn + r) * K + k0 + c4];
      *(f16x4*)&As[r * LDH + c4] =
          f16x4{(_Float16)av.x, (_Float16)av.y, (_Float16)av.z, (_Float16)av.w};
      *(f16x4*)&Bs[r * LDH + c4] =
          f16x4{(_Float16)wv.x, (_Float16)wv.y, (_Float16)wv.z, (_Float16)wv.w};
    }
    __syncthreads();
    f16x8 a[4], b[4];
#pragma unroll
    for (int mi = 0; mi < 4; ++mi)
      a[mi] = *(const f16x8*)&As[(wr + mi * 16 + lrow) * LDH + lk];
#pragma unroll
    for (int ni = 0; ni < 4; ++ni)
      b[ni] = *(const f16x8*)&Bs[(wc + ni * 16 + lrow) * LDH + lk];
#pragma unroll
    for (int mi = 0; mi < 4; ++mi)
#pragma unroll
      for (int ni = 0; ni < 4; ++ni)
        acc[mi][ni] = __builtin_amdgcn_mfma_f32_16x16x32_f16(a[mi], b[ni],
                                                             acc[mi][ni], 0, 0, 0);
    __syncthreads();
  }
#pragma unroll
  for (int mi = 0; mi < 4; ++mi)
#pragma unroll
    for (int ni = 0; ni < 4; ++ni) {
      int col = bn + wc + ni * 16 + lrow;
      float bv = bias ? bias[col] : 0.0f;
#pragma unroll
      for (int i = 0; i < 4; ++i) {
        int row = bm + wr + mi * 16 + (lane >> 4) * 4 + i;
        C[(size_t)row * N + col] = (_Float16)(acc[mi][ni][i] + bv);
      }
    }
}

// ---------------------------------------------------------------------------
// Fused S kernel:  S[n,g,m] = log(relu(emb(n,m)·Wg[g] + Wg_b[g]) + 1e-6)
//                           + dot(q[n,g,:], k[m,g,:]) * 0.125
// Block: 16 n-rows x 64 m-cols, 256 threads (4 waves, each wave owns 16 m).
// emb is computed DIRECTLY in MFMA B-fragment layout (lane = (m, dim-chunk)):
//   lane: m = m0 + w*16 + (lane&15); dims = kc*32 + (lane>>4)*8 .. +8
//   dim structure: d = kc*2 + ((lane>>4)>>1); sin-half if (lane>>4)&1==0 else cos.
// Bias C[g][m] -> LDS (f16) -> re-read in qk phase as [n][m] tiles. Same-wave
// write/read (wave's own 16 m-cols), so no __syncthreads needed.
// ---------------------------------------------------------------------------
__global__ __launch_bounds__(256) void s_fused_kernel(
    const float* __restrict__ rois_cur, const float* __restrict__ rois_ref,
    const float* __restrict__ Wg_w, const float* __restrict__ Wg_b,
    const _Float16* __restrict__ q, const _Float16* __restrict__ k,
    float* __restrict__ S) {
  __shared__ _Float16 Bias[GROUP][16][BP];  // [g][n_local][m_local(64)+pad]
  const int tid = threadIdx.x;
  const int lane = tid & 63, w = tid >> 6;
  const int n0 = blockIdx.x * 16, m0 = blockIdx.y * 64;
  const int lm = lane & 15, lc = lane >> 4;
  const int wm = w * 16;           // wave's m-tile offset within block
  const int mglob = m0 + wm + lm;  // this lane's m (MFMA B-col)

  // Wg A-fragments: row g = lm, dims kc*32 + lc*8 + j   (f32 -> f16)
  f16x8 wgf[2];
#pragma unroll
  for (int kc = 0; kc < 2; ++kc) {
    const float* p = Wg_w + lm * EMB + kc * 32 + lc * 8;
#pragma unroll
    for (int j = 0; j < 8; ++j) wgf[kc][j] = (_Float16)p[j];
  }
  float wgb[4];
#pragma unroll
  for (int i = 0; i < 4; ++i) wgb[i] = Wg_b[lc * 4 + i];

  // ref-roi constants for this lane's m
  const float4 rb = reinterpret_cast<const float4*>(rois_ref)[mglob];
  const float wr_ = rb.z - rb.x + 1.0f, hr_ = rb.w - rb.y + 1.0f;
  const float cxr = 0.5f * (rb.x + rb.z), cyr = 0.5f * (rb.y + rb.w);
  const float lwr = __logf(wr_), lhr = __logf(hr_);

  const float inv_dim[8] = {1.0f,          0.42169651f,  0.17782794f,
                            0.074989417f,  0.031622776f, 0.013335214f,
                            0.0056234133f, 0.0023713737f};
  const int isY = lc >> 1;     // 0: dx/dw dims, 1: dy/dh dims
  const int useCos = lc & 1;   // 0: sin half, 1: cos half

  // ---- bias phase: per n-row, build emb frags in-register, 2 MFMAs ----
  for (int nl = 0; nl < 16; ++nl) {
    const int n = n0 + nl;
    const float x0 = rois_cur[n * 4 + 0], y0 = rois_cur[n * 4 + 1];
    const float x1 = rois_cur[n * 4 + 2], y1 = rois_cur[n * 4 + 3];
    const float ww = x1 - x0 + 1.0f, hh = y1 - y0 + 1.0f;
    const float cx = 0.5f * (x0 + x1), cy = 0.5f * (y0 + y1);
    float pa, pb;  // pos[d] for d = isY (frag kc=0) and d = 2+isY (frag kc=1)
    if (isY) {
      pa = __logf(fabsf((cy - cyr) / hh) + 0.001f);
      pb = __logf(hh) - lhr;
    } else {
      pa = __logf(fabsf((cx - cxr) / ww) + 0.001f);
      pb = __logf(ww) - lwr;
    }
    pa *= 100.0f;
    pb *= 100.0f;
    f16x8 ef0, ef1;
#pragma unroll
    for (int f = 0; f < 8; ++f) {
      const float xa = pa * inv_dim[f];
      const float xb = pb * inv_dim[f];
      ef0[f] = (_Float16)(useCos ? __cosf(xa) : __sinf(xa));
      ef1[f] = (_Float16)(useCos ? __cosf(xb) : __sinf(xb));
    }
    f32x4 acc = {};
    acc = __builtin_amdgcn_mfma_f32_16x16x32_f16(wgf[0], ef0, acc, 0, 0, 0);
    acc = __builtin_amdgcn_mfma_f32_16x16x32_f16(wgf[1], ef1, acc, 0, 0, 0);
#pragma unroll
    for (int i = 0; i < 4; ++i) {
      float v = fmaxf(acc[i] + wgb[i], 0.0f);
      Bias[lc * 4 + i][nl][wm + lm] = (_Float16)__logf(v + 1e-6f);
    }
  }

  // ---- qk phase: per g, 16n x 16m MFMA (K=64), add bias, store S ----
  for (int g = 0; g < GROUP; ++g) {
    f16x8 qa0 = *(const f16x8*)&q[(size_t)(n0 + lm) * FEAT + g * DG + lc * 8];
    f16x8 qa1 = *(const f16x8*)&q[(size_t)(n0 + lm) * FEAT + g * DG + 32 + lc * 8];
    f16x8 kb0 = *(const f16x8*)&k[(size_t)mglob * FEAT + g * DG + lc * 8];
    f16x8 kb1 = *(const f16x8*)&k[(size_t)mglob * FEAT + g * DG + 32 + lc * 8];
    f32x4 acc = {};
    acc = __builtin_amdgcn_mfma_f32_16x16x32_f16(qa0, kb0, acc, 0, 0, 0);
    acc = __builtin_amdgcn_mfma_f32_16x16x32_f16(qa1, kb1, acc, 0, 0, 0);
#pragma unroll
    for (int i = 0; i < 4; ++i) {
      const int r = lc * 4 + i;
      float bl = (float)Bias[g][r][wm + lm];
      S[((size_t)(n0 + r) * GROUP + g) * M_REF + m0 + wm + lm] =
          bl + acc[i] * 0.125f;
    }
  }
}

// ---------------------------------------------------------------------------
// Fused softmax + PV: out[n, g*64+c] = softmax_m(S[n,g,:]) · Vt[g*64+c, :] + b
// Block: (16 n-rows, one g), 256 threads; wave w owns m in [w*1024,(w+1)*1024).
// Online softmax; P is built directly in MFMA A-frag layout (row=lane&15,
// k-offset=(lane>>4)*8 == the S-read layout). 4-wave combine via LDS.
// ---------------------------------------------------------------------------
__global__ __launch_bounds__(256) void pv_fused_kernel(
    const float* __restrict__ S, const _Float16* __restrict__ vt,
    const float* __restrict__ Wv_b, float* __restrict__ out) {
  __shared__ float wacc[4][16][64];
  __shared__ float wm_[4][16], wl_[4][16];
  const int tid = threadIdx.x, lane = tid & 63, w = tid >> 6;
  const int n0 = blockIdx.x * 16, g = blockIdx.y;
  const int lm = lane & 15, lc = lane >> 4;
  const size_t srow = ((size_t)(n0 + lm) * GROUP + g) * M_REF;

  f32x4 acc[4] = {};
  float mrun = -1e30f, lrun = 0.0f;

  for (int mc = 0; mc < 32; ++mc) {
    const int mb = w * 1024 + mc * 32;
    const float4 sa = *(const float4*)&S[srow + mb + lc * 8];
    const float4 sb = *(const float4*)&S[srow + mb + lc * 8 + 4];
    float cmax = fmaxf(fmaxf(fmaxf(sa.x, sa.y), fmaxf(sa.z, sa.w)),
                       fmaxf(fmaxf(sb.x, sb.y), fmaxf(sb.z, sb.w)));
    cmax = fmaxf(cmax, __shfl_xor(cmax, 16));
    cmax = fmaxf(cmax, __shfl_xor(cmax, 32));
    const float mnew = fmaxf(mrun, cmax);
    const float fac = __expf(mrun - mnew);
    float p[8];
    p[0] = __expf(sa.x - mnew); p[1] = __expf(sa.y - mnew);
    p[2] = __expf(sa.z - mnew); p[3] = __expf(sa.w - mnew);
    p[4] = __expf(sb.x - mnew); p[5] = __expf(sb.y - mnew);
    p[6] = __expf(sb.z - mnew); p[7] = __expf(sb.w - mnew);
    float csum = ((p[0] + p[1]) + (p[2] + p[3])) + ((p[4] + p[5]) + (p[6] + p[7]));
    csum += __shfl_xor(csum, 16);
    csum += __shfl_xor(csum, 32);
    lrun = lrun * fac + csum;
    mrun = mnew;
    f16x8 af;
#pragma unroll
    for (int j = 0; j < 8; ++j) af[j] = (_Float16)p[j];
    float fr[4];
#pragma unroll
    for (int i = 0; i < 4; ++i) fr[i] = __shfl(fac, lc * 4 + i);
#pragma unroll
    for (int ct = 0; ct < 4; ++ct) {
      f16x8 bf = *(const f16x8*)
          &vt[(size_t)(g * DG + ct * 16 + lm) * M_REF + mb + lc * 8];
#pragma unroll
      for (int i = 0; i < 4; ++i) acc[ct][i] *= fr[i];
      acc[ct] = __builtin_amdgcn_mfma_f32_16x16x32_f16(af, bf, acc[ct], 0, 0, 0);
    }
  }

  // per-wave partials -> LDS
#pragma unroll
  for (int ct = 0; ct < 4; ++ct)
#pragma unroll
    for (int i = 0; i < 4; ++i)
      wacc[w][lc * 4 + i][ct * 16 + lm] = acc[ct][i];
  if (lane < 16) {
    wm_[w][lane] = mrun;
    wl_[w][lane] = lrun;
  }
  __syncthreads();

  // combine: thread t -> row r = t>>4, cols (t&15)*4 .. +3
  const int r = tid >> 4, c0 = (tid & 15) * 4;
  const float M = fmaxf(fmaxf(wm_[0][r], wm_[1][r]), fmaxf(wm_[2][r], wm_[3][r]));
  float e[4], D = 0.0f;
#pragma unroll
  for (int ww = 0; ww < 4; ++ww) {
    e[ww] = __expf(wm_[ww][r] - M);
    D += e[ww] * wl_[ww][r];
  }
  const float inv = 1.0f / D;
  float4 o;
  float* po = &o.x;
#pragma unroll
  for (int j = 0; j < 4; ++j) {
    float s = 0.0f;
#pragma unroll
    for (int ww = 0; ww < 4; ++ww) s += e[ww] * wacc[ww][r][c0 + j];
    po[j] = s * inv + Wv_b[g * DG + c0 + j];
  }
  *(float4*)&out[(size_t)(n0 + r) * FEAT + g * DG + c0] = o;
}

// ---------------------------------------------------------------------------
extern "C" void kernel_launch(void* const* d_in, const int* in_sizes, int n_in,
                              void* d_out, int out_size, void* d_ws,
                              size_t ws_size, hipStream_t stream) {
  const float* roi_feat = (const float*)d_in[0];   // [512,1024]
  const float* ref_feat = (const float*)d_in[1];   // [4096,1024]
  const float* rois_cur = (const float*)d_in[2];   // [512,4]
  const float* rois_ref = (const float*)d_in[3];   // [4096,4]
  const float* Wg_w = (const float*)d_in[4];       // [16,64]
  const float* Wg_b = (const float*)d_in[5];       // [16]
  const float* Wq_w = (const float*)d_in[6];       // [1024,1024]
  const float* Wq_b = (const float*)d_in[7];       // [1024]
  const float* Wk_w = (const float*)d_in[8];       // [1024,1024]
  const float* Wk_b = (const float*)d_in[9];       // [1024]
  const float* Wv_w = (const float*)d_in[10];      // [1024,1024]
  const float* Wv_b = (const float*)d_in[11];      // [1024]
  float* out = (float*)d_out;                      // [512,1024]

  _Float16* q16 = (_Float16*)d_ws;                     // 512*1024
  _Float16* k16 = q16 + (size_t)N_ROI * FEAT;          // 4096*1024
  _Float16* vt16 = k16 + (size_t)M_REF * FEAT;         // 1024*4096 (V transposed)
  float* S = (float*)(vt16 + (size_t)FEAT * M_REF);    // 512*16*4096

  // 1. projections (f16 MFMA). Vt computed directly transposed (no bias;
  //    Wv_b added in pv epilogue since softmax rows sum to 1).
  gemm_nt_f16<<<dim3(FEAT / 128, N_ROI / 128), 256, 0, stream>>>(
      roi_feat, Wq_w, Wq_b, q16, N_ROI, FEAT, FEAT);
  gemm_nt_f16<<<dim3(FEAT / 128, M_REF / 128), 256, 0, stream>>>(
      ref_feat, Wk_w, Wk_b, k16, M_REF, FEAT, FEAT);
  gemm_nt_f16<<<dim3(M_REF / 128, FEAT / 128), 256, 0, stream>>>(
      Wv_w, ref_feat, nullptr, vt16, FEAT, M_REF, FEAT);

  // 2. fused S = positional log-bias + scaled qk   (writes S exactly once)
  s_fused_kernel<<<dim3(N_ROI / 16, M_REF / 64), 256, 0, stream>>>(
      rois_cur, rois_ref, Wg_w, Wg_b, q16, k16, S);

  // 3. fused online-softmax + PV + bias            (reads S exactly once)
  pv_fused_kernel<<<dim3(N_ROI / 16, GROUP), 256, 0, stream>>>(
      S, vt16, Wv_b, out);
}

// Round 5
// 272.687 us; speedup vs baseline: 19.6427x; 1.3686x over previous
//
#include <hip/hip_runtime.h>
#include <hip/hip_bf16.h>

#define N_ROI 512
#define M_REF 4096
#define FEAT 1024
#define GROUP 16
#define DG 64
#define EMB 64
#define BP 68    // Bias LDS col pad (halfs)
#define GLDH 72  // gemm LDS row stride (halfs): 64 + 8 pad -> <=2-way conflicts

using f16x8 = __attribute__((ext_vector_type(8))) _Float16;
using f16x4 = __attribute__((ext_vector_type(4))) _Float16;
using f32x4 = __attribute__((ext_vector_type(4))) float;

// ---------------------------------------------------------------------------
// One-shot fp32 -> f16 cast of 5 tensors (vectorized float4 -> f16x4).
// ---------------------------------------------------------------------------
__global__ __launch_bounds__(256) void cast_f16_5(
    const float* __restrict__ s0, _Float16* __restrict__ d0, int n0,
    const float* __restrict__ s1, _Float16* __restrict__ d1, int n1,
    const float* __restrict__ s2, _Float16* __restrict__ d2, int n2,
    const float* __restrict__ s3, _Float16* __restrict__ d3, int n3,
    const float* __restrict__ s4, _Float16* __restrict__ d4, int n4) {
  const int q0 = n0 >> 2, q1 = n1 >> 2, q2 = n2 >> 2, q3 = n3 >> 2, q4 = n4 >> 2;
  const int total = q0 + q1 + q2 + q3 + q4;
  for (int i = blockIdx.x * 256 + threadIdx.x; i < total;
       i += gridDim.x * 256) {
    int j = i;
    const float* s;
    _Float16* d;
    if (j < q0) { s = s0; d = d0; }
    else { j -= q0;
      if (j < q1) { s = s1; d = d1; }
      else { j -= q1;
        if (j < q2) { s = s2; d = d2; }
        else { j -= q2;
          if (j < q3) { s = s3; d = d3; }
          else { j -= q3; s = s4; d = d4; } } } }
    float4 v = *(const float4*)&s[(size_t)j * 4];
    *(f16x4*)&d[(size_t)j * 4] =
        f16x4{(_Float16)v.x, (_Float16)v.y, (_Float16)v.z, (_Float16)v.w};
  }
}

// ---------------------------------------------------------------------------
// Pure-f16 NT GEMM: C[i,j] = (f16)( sum_k A[i,k]*B[j,k] + bias[j] )
// Tile 128(M) x 64(N) x BK=64; 256 threads = 4 waves (2x2), wave = 64x32.
// Reg-staged prefetch: next K-tile's global loads issue before MFMA phase.
// ---------------------------------------------------------------------------
__global__ __launch_bounds__(256) void gemm_ff16(
    const _Float16* __restrict__ A, const _Float16* __restrict__ B,
    const float* __restrict__ bias, _Float16* __restrict__ C,
    int M, int N, int K) {
  __shared__ _Float16 As[128 * GLDH];
  __shared__ _Float16 Bs[64 * GLDH];
  const int tid = threadIdx.x, lane = tid & 63, wid = tid >> 6;
  const int bm = blockIdx.y * 128, bn = blockIdx.x * 64;
  const int wr = (wid >> 1) * 64, wc = (wid & 1) * 32;
  const int lrow = lane & 15, lk = (lane >> 4) * 8;

  f16x8 ra[4], rb[2];
#pragma unroll
  for (int i = 0; i < 4; ++i) {
    int idx = tid + i * 256, r = idx >> 3, c = (idx & 7) * 8;
    ra[i] = *(const f16x8*)&A[(size_t)(bm + r) * K + c];
  }
#pragma unroll
  for (int i = 0; i < 2; ++i) {
    int idx = tid + i * 256, r = idx >> 3, c = (idx & 7) * 8;
    rb[i] = *(const f16x8*)&B[(size_t)(bn + r) * K + c];
  }

  f32x4 acc[4][2] = {};
  for (int k0 = 0; k0 < K; k0 += 64) {
#pragma unroll
    for (int i = 0; i < 4; ++i) {
      int idx = tid + i * 256, r = idx >> 3, c = (idx & 7) * 8;
      *(f16x8*)&As[r * GLDH + c] = ra[i];
    }
#pragma unroll
    for (int i = 0; i < 2; ++i) {
      int idx = tid + i * 256, r = idx >> 3, c = (idx & 7) * 8;
      *(f16x8*)&Bs[r * GLDH + c] = rb[i];
    }
    __syncthreads();
    if (k0 + 64 < K) {
#pragma unroll
      for (int i = 0; i < 4; ++i) {
        int idx = tid + i * 256, r = idx >> 3, c = (idx & 7) * 8;
        ra[i] = *(const f16x8*)&A[(size_t)(bm + r) * K + k0 + 64 + c];
      }
#pragma unroll
      for (int i = 0; i < 2; ++i) {
        int idx = tid + i * 256, r = idx >> 3, c = (idx & 7) * 8;
        rb[i] = *(const f16x8*)&B[(size_t)(bn + r) * K + k0 + 64 + c];
      }
    }
    f16x8 a[4][2], b[2][2];
#pragma unroll
    for (int mi = 0; mi < 4; ++mi)
#pragma unroll
      for (int ks = 0; ks < 2; ++ks)
        a[mi][ks] = *(const f16x8*)&As[(wr + mi * 16 + lrow) * GLDH + ks * 32 + lk];
#pragma unroll
    for (int ni = 0; ni < 2; ++ni)
#pragma unroll
      for (int ks = 0; ks < 2; ++ks)
        b[ni][ks] = *(const f16x8*)&Bs[(wc + ni * 16 + lrow) * GLDH + ks * 32 + lk];
#pragma unroll
    for (int ks = 0; ks < 2; ++ks)
#pragma unroll
      for (int mi = 0; mi < 4; ++mi)
#pragma unroll
        for (int ni = 0; ni < 2; ++ni)
          acc[mi][ni] = __builtin_amdgcn_mfma_f32_16x16x32_f16(
              a[mi][ks], b[ni][ks], acc[mi][ni], 0, 0, 0);
    __syncthreads();
  }
#pragma unroll
  for (int mi = 0; mi < 4; ++mi)
#pragma unroll
    for (int ni = 0; ni < 2; ++ni) {
      int col = bn + wc + ni * 16 + lrow;
      float bv = bias ? bias[col] : 0.0f;
#pragma unroll
      for (int i = 0; i < 4; ++i) {
        int row = bm + wr + mi * 16 + (lane >> 4) * 4 + i;
        C[(size_t)row * N + col] = (_Float16)(acc[mi][ni][i] + bv);
      }
    }
}

// ---------------------------------------------------------------------------
// Fused S kernel (R4 structure + unrolls):
//   S[n,g,m] = log(relu(emb·Wg + b) + 1e-6) + qk*0.125
// ---------------------------------------------------------------------------
__global__ __launch_bounds__(256) void s_fused_kernel(
    const float* __restrict__ rois_cur, const float* __restrict__ rois_ref,
    const float* __restrict__ Wg_w, const float* __restrict__ Wg_b,
    const _Float16* __restrict__ q, const _Float16* __restrict__ k,
    float* __restrict__ S) {
  __shared__ _Float16 Bias[GROUP][16][BP];
  const int tid = threadIdx.x;
  const int lane = tid & 63, w = tid >> 6;
  const int n0 = blockIdx.x * 16, m0 = blockIdx.y * 64;
  const int lm = lane & 15, lc = lane >> 4;
  const int wm = w * 16;
  const int mglob = m0 + wm + lm;

  f16x8 wgf[2];
#pragma unroll
  for (int kc = 0; kc < 2; ++kc) {
    const float* p = Wg_w + lm * EMB + kc * 32 + lc * 8;
#pragma unroll
    for (int j = 0; j < 8; ++j) wgf[kc][j] = (_Float16)p[j];
  }
  float wgb[4];
#pragma unroll
  for (int i = 0; i < 4; ++i) wgb[i] = Wg_b[lc * 4 + i];

  const float4 rb = reinterpret_cast<const float4*>(rois_ref)[mglob];
  const float wr_ = rb.z - rb.x + 1.0f, hr_ = rb.w - rb.y + 1.0f;
  const float cxr = 0.5f * (rb.x + rb.z), cyr = 0.5f * (rb.y + rb.w);
  const float lwr = __logf(wr_), lhr = __logf(hr_);

  const float inv_dim[8] = {1.0f,          0.42169651f,  0.17782794f,
                            0.074989417f,  0.031622776f, 0.013335214f,
                            0.0056234133f, 0.0023713737f};
  const int isY = lc >> 1;
  const int useCos = lc & 1;

#pragma unroll 2
  for (int nl = 0; nl < 16; ++nl) {
    const int n = n0 + nl;
    const float x0 = rois_cur[n * 4 + 0], y0 = rois_cur[n * 4 + 1];
    const float x1 = rois_cur[n * 4 + 2], y1 = rois_cur[n * 4 + 3];
    const float ww = x1 - x0 + 1.0f, hh = y1 - y0 + 1.0f;
    const float cx = 0.5f * (x0 + x1), cy = 0.5f * (y0 + y1);
    float pa, pb;
    if (isY) {
      pa = __logf(fabsf((cy - cyr) / hh) + 0.001f);
      pb = __logf(hh) - lhr;
    } else {
      pa = __logf(fabsf((cx - cxr) / ww) + 0.001f);
      pb = __logf(ww) - lwr;
    }
    pa *= 100.0f;
    pb *= 100.0f;
    f16x8 ef0, ef1;
#pragma unroll
    for (int f = 0; f < 8; ++f) {
      const float xa = pa * inv_dim[f];
      const float xb = pb * inv_dim[f];
      ef0[f] = (_Float16)(useCos ? __cosf(xa) : __sinf(xa));
      ef1[f] = (_Float16)(useCos ? __cosf(xb) : __sinf(xb));
    }
    f32x4 acc = {};
    acc = __builtin_amdgcn_mfma_f32_16x16x32_f16(wgf[0], ef0, acc, 0, 0, 0);
    acc = __builtin_amdgcn_mfma_f32_16x16x32_f16(wgf[1], ef1, acc, 0, 0, 0);
#pragma unroll
    for (int i = 0; i < 4; ++i) {
      float v = fmaxf(acc[i] + wgb[i], 0.0f);
      Bias[lc * 4 + i][nl][wm + lm] = (_Float16)__logf(v + 1e-6f);
    }
  }

#pragma unroll 2
  for (int g = 0; g < GROUP; ++g) {
    f16x8 qa0 = *(const f16x8*)&q[(size_t)(n0 + lm) * FEAT + g * DG + lc * 8];
    f16x8 qa1 = *(const f16x8*)&q[(size_t)(n0 + lm) * FEAT + g * DG + 32 + lc * 8];
    f16x8 kb0 = *(const f16x8*)&k[(size_t)mglob * FEAT + g * DG + lc * 8];
    f16x8 kb1 = *(const f16x8*)&k[(size_t)mglob * FEAT + g * DG + 32 + lc * 8];
    f32x4 acc = {};
    acc = __builtin_amdgcn_mfma_f32_16x16x32_f16(qa0, kb0, acc, 0, 0, 0);
    acc = __builtin_amdgcn_mfma_f32_16x16x32_f16(qa1, kb1, acc, 0, 0, 0);
#pragma unroll
    for (int i = 0; i < 4; ++i) {
      const int r = lc * 4 + i;
      float bl = (float)Bias[g][r][wm + lm];
      S[((size_t)(n0 + r) * GROUP + g) * M_REF + m0 + wm + lm] =
          bl + acc[i] * 0.125f;
    }
  }
}

// ---------------------------------------------------------------------------
// Fused softmax + PV, 512 threads / 8 waves; wave w owns m in [w*512,(w+1)*512).
// ---------------------------------------------------------------------------
__global__ __launch_bounds__(512) void pv_fused_kernel(
    const float* __restrict__ S, const _Float16* __restrict__ vt,
    const float* __restrict__ Wv_b, float* __restrict__ out) {
  __shared__ float wacc[8][16][64];
  __shared__ float wm_[8][16], wl_[8][16];
  const int tid = threadIdx.x, lane = tid & 63, w = tid >> 6;
  const int n0 = blockIdx.x * 16, g = blockIdx.y;
  const int lm = lane & 15, lc = lane >> 4;
  const size_t srow = ((size_t)(n0 + lm) * GROUP + g) * M_REF;

  f32x4 acc[4] = {};
  float mrun = -1e30f, lrun = 0.0f;

#pragma unroll 2
  for (int mc = 0; mc < 16; ++mc) {
    const int mb = w * 512 + mc * 32;
    const float4 sa = *(const float4*)&S[srow + mb + lc * 8];
    const float4 sb = *(const float4*)&S[srow + mb + lc * 8 + 4];
    float cmax = fmaxf(fmaxf(fmaxf(sa.x, sa.y), fmaxf(sa.z, sa.w)),
                       fmaxf(fmaxf(sb.x, sb.y), fmaxf(sb.z, sb.w)));
    cmax = fmaxf(cmax, __shfl_xor(cmax, 16));
    cmax = fmaxf(cmax, __shfl_xor(cmax, 32));
    const float mnew = fmaxf(mrun, cmax);
    const float fac = __expf(mrun - mnew);
    float p[8];
    p[0] = __expf(sa.x - mnew); p[1] = __expf(sa.y - mnew);
    p[2] = __expf(sa.z - mnew); p[3] = __expf(sa.w - mnew);
    p[4] = __expf(sb.x - mnew); p[5] = __expf(sb.y - mnew);
    p[6] = __expf(sb.z - mnew); p[7] = __expf(sb.w - mnew);
    float csum = ((p[0] + p[1]) + (p[2] + p[3])) + ((p[4] + p[5]) + (p[6] + p[7]));
    csum += __shfl_xor(csum, 16);
    csum += __shfl_xor(csum, 32);
    lrun = lrun * fac + csum;
    mrun = mnew;
    f16x8 af;
#pragma unroll
    for (int j = 0; j < 8; ++j) af[j] = (_Float16)p[j];
    float fr[4];
#pragma unroll
    for (int i = 0; i < 4; ++i) fr[i] = __shfl(fac, lc * 4 + i);
#pragma unroll
    for (int ct = 0; ct < 4; ++ct) {
      f16x8 bf = *(const f16x8*)
          &vt[(size_t)(g * DG + ct * 16 + lm) * M_REF + mb + lc * 8];
#pragma unroll
      for (int i = 0; i < 4; ++i) acc[ct][i] *= fr[i];
      acc[ct] = __builtin_amdgcn_mfma_f32_16x16x32_f16(af, bf, acc[ct], 0, 0, 0);
    }
  }

#pragma unroll
  for (int ct = 0; ct < 4; ++ct)
#pragma unroll
    for (int i = 0; i < 4; ++i)
      wacc[w][lc * 4 + i][ct * 16 + lm] = acc[ct][i];
  if (lane < 16) {
    wm_[w][lane] = mrun;
    wl_[w][lane] = lrun;
  }
  __syncthreads();

  if (tid < 256) {
    const int r = tid >> 4, c0 = (tid & 15) * 4;
    float M = -1e30f;
#pragma unroll
    for (int ww = 0; ww < 8; ++ww) M = fmaxf(M, wm_[ww][r]);
    float e[8], D = 0.0f;
#pragma unroll
    for (int ww = 0; ww < 8; ++ww) {
      e[ww] = __expf(wm_[ww][r] - M);
      D += e[ww] * wl_[ww][r];
    }
    const float inv = 1.0f / D;
    float4 o;
    float* po = &o.x;
#pragma unroll
    for (int j = 0; j < 4; ++j) {
      float s = 0.0f;
#pragma unroll
      for (int ww = 0; ww < 8; ++ww) s += e[ww] * wacc[ww][r][c0 + j];
      po[j] = s * inv + Wv_b[g * DG + c0 + j];
    }
    *(float4*)&out[(size_t)(n0 + r) * FEAT + g * DG + c0] = o;
  }
}

// ---------------------------------------------------------------------------
extern "C" void kernel_launch(void* const* d_in, const int* in_sizes, int n_in,
                              void* d_out, int out_size, void* d_ws,
                              size_t ws_size, hipStream_t stream) {
  const float* roi_feat = (const float*)d_in[0];   // [512,1024]
  const float* ref_feat = (const float*)d_in[1];   // [4096,1024]
  const float* rois_cur = (const float*)d_in[2];   // [512,4]
  const float* rois_ref = (const float*)d_in[3];   // [4096,4]
  const float* Wg_w = (const float*)d_in[4];       // [16,64]
  const float* Wg_b = (const float*)d_in[5];       // [16]
  const float* Wq_w = (const float*)d_in[6];       // [1024,1024]
  const float* Wq_b = (const float*)d_in[7];       // [1024]
  const float* Wk_w = (const float*)d_in[8];       // [1024,1024]
  const float* Wk_b = (const float*)d_in[9];       // [1024]
  const float* Wv_w = (const float*)d_in[10];      // [1024,1024]
  const float* Wv_b = (const float*)d_in[11];      // [1024]
  float* out = (float*)d_out;                      // [512,1024]

  _Float16* q16 = (_Float16*)d_ws;                     // 512*1024
  _Float16* k16 = q16 + (size_t)N_ROI * FEAT;          // 4096*1024
  _Float16* vt16 = k16 + (size_t)M_REF * FEAT;         // 1024*4096
  _Float16* roi16 = vt16 + (size_t)FEAT * M_REF;       // 512*1024
  _Float16* ref16 = roi16 + (size_t)N_ROI * FEAT;      // 4096*1024
  _Float16* wq16 = ref16 + (size_t)M_REF * FEAT;       // 1024*1024
  _Float16* wk16 = wq16 + (size_t)FEAT * FEAT;         // 1024*1024
  _Float16* wv16 = wk16 + (size_t)FEAT * FEAT;         // 1024*1024
  float* S = (float*)(wv16 + (size_t)FEAT * FEAT);     // 512*16*4096 f32

  // 0. cast everything fp32 -> f16 once
  cast_f16_5<<<dim3(2048), 256, 0, stream>>>(
      roi_feat, roi16, N_ROI * FEAT, ref_feat, ref16, M_REF * FEAT,
      Wq_w, wq16, FEAT * FEAT, Wk_w, wk16, FEAT * FEAT,
      Wv_w, wv16, FEAT * FEAT);

  // 1. projections (pure-f16 MFMA GEMMs)
  gemm_ff16<<<dim3(FEAT / 64, N_ROI / 128), 256, 0, stream>>>(
      roi16, wq16, Wq_b, q16, N_ROI, FEAT, FEAT);
  gemm_ff16<<<dim3(FEAT / 64, M_REF / 128), 256, 0, stream>>>(
      ref16, wk16, Wk_b, k16, M_REF, FEAT, FEAT);
  gemm_ff16<<<dim3(M_REF / 64, FEAT / 128), 256, 0, stream>>>(
      wv16, ref16, nullptr, vt16, FEAT, M_REF, FEAT);

  // 2. fused S = positional log-bias + scaled qk
  s_fused_kernel<<<dim3(N_ROI / 16, M_REF / 64), 256, 0, stream>>>(
      rois_cur, rois_ref, Wg_w, Wg_b, q16, k16, S);

  // 3. fused online-softmax + PV + bias
  pv_fused_kernel<<<dim3(N_ROI / 16, GROUP), 512, 0, stream>>>(
      S, vt16, Wv_b, out);
}